// Round 15
// baseline (12890.773 us; speedup 1.0000x reference)
//
#include <hip/hip_runtime.h>
#include <cstddef>

#define NB 4
#define NS 1024
#define ND 384
#define NN 16
#define MTOT 4096

// ============ fused direction: LN1(3 rows) + conv3(xp) + K=1 conv + LN2 + dbc + delta ============
// One block per output row m (s in the direction's own domain). No XN/CONV buffers.
__global__ __launch_bounds__(384) void dir_all(
    const float* __restrict__ x, int flip,
    const float* __restrict__ w_p2, const float* __restrict__ b_p2,
    const float* __restrict__ g_n,  const float* __restrict__ bt_n,
    const float* __restrict__ w_c,  const float* __restrict__ b_c,
    const float* __restrict__ g,    const float* __restrict__ bt,
    const float* __restrict__ w_dbc, const float* __restrict__ w_dt,
    const float* __restrict__ b_dt,
    float* __restrict__ LNo, float* __restrict__ DBCo, float* __restrict__ DELo)
{
    __shared__ float xn[3][ND];
    __shared__ float xp[ND];
    __shared__ float u[ND];
    __shared__ float dbc[56];
    __shared__ float sh[ND];
    int m = blockIdx.x, t = threadIdx.x;
    int b = m >> 10, s = m & 1023;
    int sE = flip ? (1023 - s) : s;

    // LN1 of x rows sE-1, sE, sE+1 (zero for out-of-range: conv zero-pad is on post-LN input)
    for (int j = 0; j < 3; ++j) {
        int r = sE + j - 1;                    // block-uniform
        if (r < 0 || r >= NS) {
            xn[j][t] = 0.f;
            __syncthreads();
        } else {
            sh[t] = x[((size_t)(b * NS + r)) * ND + t];
            __syncthreads();
            float mu = 0.f;
            for (int i = 0; i < ND; ++i) mu += sh[i];
            mu *= (1.f / ND);
            float vr = 0.f;
            for (int i = 0; i < ND; ++i) { float dd = sh[i] - mu; vr += dd * dd; }
            vr *= (1.f / ND);
            float v = sh[t];
            __syncthreads();                    // sh reads done before next j overwrites
            xn[j][t] = (v - mu) * rsqrtf(vr + 1e-5f) * g_n[t] + bt_n[t];
        }
    }
    __syncthreads();

    // conv3 (cross-correlation): xp[t] = b_p2[t] + sum_k sum_i xn[k][i] * w_p2[t][i][k]
    {
        float a = b_p2[t];
        const float* wbase = w_p2 + (size_t)t * 1152;
        for (int k = 0; k < 3; ++k) {
            const float* wr = wbase + k;
            const float* xr = xn[k];
            for (int i = 0; i < ND; ++i) a += xr[i] * wr[i * 3];
        }
        xp[t] = a;
    }
    __syncthreads();

    // K=1 conv: u[t] = b_c[t] + sum_i xp[i] * w_c[t][i]
    float a = b_c[t];
    {
        const float* wr = w_c + (size_t)t * ND;
        for (int i = 0; i < ND; ++i) a += xp[i] * wr[i];
    }
    u[t] = a;
    __syncthreads();
    // LN2
    float mu = 0.f;
    for (int i = 0; i < ND; ++i) mu += u[i];
    mu *= (1.f / ND);
    float vr = 0.f;
    for (int i = 0; i < ND; ++i) { float dd = u[i] - mu; vr += dd * dd; }
    vr *= (1.f / ND);
    float ln = (a - mu) * rsqrtf(vr + 1e-5f) * g[t] + bt[t];
    __syncthreads();                            // all u reads done before overwrite
    u[t] = ln;
    LNo[(size_t)m * ND + t] = ln;
    __syncthreads();
    // dbc projection (rows 0..55 of w_dbc)
    if (t < 56) {
        float ad = 0.f;
        const float* wd = w_dbc + (size_t)t * ND;
        for (int i = 0; i < ND; ++i) ad += u[i] * wd[i];
        dbc[t] = ad;
        DBCo[(size_t)m * 56 + t] = ad;
    }
    __syncthreads();
    // delta = softplus(dbc[0..23] . w_dt[t] + b_dt[t])
    float acc = b_dt[t];
    {
        const float* wt = w_dt + (size_t)t * 24;
        for (int r = 0; r < 24; ++r) acc += dbc[r] * wt[r];
    }
    DELo[(size_t)m * ND + t] = fmaxf(acc, 0.f) + log1pf(expf(-fabsf(acc)));
}

// ============ selective scan: one thread per (b,d) ============
__global__ __launch_bounds__(256) void scan_naive(
    const float* __restrict__ delta, const float* __restrict__ u,
    const float* __restrict__ dbc, const float* __restrict__ A_log,
    const float* __restrict__ Dv, float* __restrict__ y_out)
{
    int gd = blockIdx.x * 256 + threadIdx.x;
    if (gd >= NB * ND) return;
    int d = gd % ND, b = gd / ND;
    float A[NN], h[NN];
    for (int n = 0; n < NN; ++n) { A[n] = -expf(A_log[(size_t)d * NN + n]); h[n] = 0.f; }
    float Dd = Dv[d];
    for (int s = 0; s < NS; ++s) {
        size_t rix = (size_t)b * NS + s;
        float dl = delta[rix * ND + d];
        float uv = u[rix * ND + d];
        float dx = dl * uv;
        const float* r = dbc + rix * 56;
        float y = 0.f;
        for (int n = 0; n < NN; ++n) {
            float da = expf(dl * A[n]);
            h[n] = da * h[n] + dx * r[24 + n];   // B cols 24..39
            y += h[n] * r[40 + n];               // C cols 40..55
        }
        y_out[rix * ND + d] = y + Dd * uv;
    }
}

// ============ final: LN1(3 rows) + conv3(z1 gate) + combine + projection + skip ============
__global__ __launch_bounds__(384) void final_all(
    const float* __restrict__ x,
    const float* __restrict__ w_p1, const float* __restrict__ b_p1,
    const float* __restrict__ g_n,  const float* __restrict__ bt_n,
    const float* __restrict__ YF,   const float* __restrict__ YB,
    const float* __restrict__ w_p3, const float* __restrict__ b_p3,
    float* __restrict__ out)
{
    __shared__ float xn[3][ND];
    __shared__ float x3[ND];
    __shared__ float sh[ND];
    int m = blockIdx.x, t = threadIdx.x;
    int b = m >> 10, s = m & 1023;

    for (int j = 0; j < 3; ++j) {
        int r = s + j - 1;
        if (r < 0 || r >= NS) {
            xn[j][t] = 0.f;
            __syncthreads();
        } else {
            sh[t] = x[((size_t)(b * NS + r)) * ND + t];
            __syncthreads();
            float mu = 0.f;
            for (int i = 0; i < ND; ++i) mu += sh[i];
            mu *= (1.f / ND);
            float vr = 0.f;
            for (int i = 0; i < ND; ++i) { float dd = sh[i] - mu; vr += dd * dd; }
            vr *= (1.f / ND);
            float v = sh[t];
            __syncthreads();
            xn[j][t] = (v - mu) * rsqrtf(vr + 1e-5f) * g_n[t] + bt_n[t];
        }
    }
    __syncthreads();

    // z1 gate from w_p1 (cross-correlation)
    float z = b_p1[t];
    {
        const float* wbase = w_p1 + (size_t)t * 1152;
        for (int k = 0; k < 3; ++k) {
            const float* wr = wbase + k;
            const float* xr = xn[k];
            for (int i = 0; i < ND; ++i) z += xr[i] * wr[i * 3];
        }
    }
    float sz = z / (1.f + expf(-z));
    x3[t] = (YF[(size_t)m * ND + t] + YB[(size_t)m * ND + t]) * sz;
    __syncthreads();

    float a = b_p3[t];
    const float* wr = w_p3 + (size_t)t * ND;
    for (int i = 0; i < ND; ++i) a += x3[i] * wr[i];
    out[(size_t)m * ND + t] = a + x[(size_t)m * ND + t];
}

__global__ __launch_bounds__(256) void fill_f32(float* out, float v, int n)
{
    int i = blockIdx.x * 256 + threadIdx.x;
    if (i < n) out[i] = v;
}

// ============ launch ============
extern "C" void kernel_launch(void* const* d_in, const int* in_sizes, int n_in,
                              void* d_out, int out_size, void* d_ws, size_t ws_size,
                              hipStream_t stream) {
    float* out = (float*)d_out;   // f32; harness truncates both sides to bf16 grid for compare

    if (out_size != MTOT * ND) {
        fill_f32<<<(out_size + 255) / 256, 256, 0, stream>>>(
            out, 70000.f + (float)(out_size >> 16), out_size);
        return;
    }
    // ws: LNF, DELF, YF, LNB, DELB, YB (6 x 1572864) + DBCF, DBCB (2 x 229376)
    const size_t ws_need = ((size_t)MTOT * ND * 6 + (size_t)MTOT * 56 * 2) * sizeof(float);
    if (ws_size < ws_need) {
        fill_f32<<<(out_size + 255) / 256, 256, 0, stream>>>(out, 60000.f, out_size);
        return;
    }

    const float* x      = (const float*)d_in[0];
    const float* w_p1   = (const float*)d_in[1];
    const float* b_p1   = (const float*)d_in[2];
    const float* w_p2   = (const float*)d_in[3];
    const float* b_p2   = (const float*)d_in[4];
    const float* w_p3   = (const float*)d_in[5];
    const float* b_p3   = (const float*)d_in[6];
    const float* w_cf   = (const float*)d_in[7];
    const float* b_cf   = (const float*)d_in[8];
    const float* w_cb   = (const float*)d_in[9];
    const float* b_cb   = (const float*)d_in[10];
    const float* g_n    = (const float*)d_in[11];
    const float* bt_n   = (const float*)d_in[12];
    const float* g_nf   = (const float*)d_in[13];
    const float* bt_nf  = (const float*)d_in[14];
    const float* g_nb   = (const float*)d_in[15];
    const float* bt_nb  = (const float*)d_in[16];
    const float* w_dbc1 = (const float*)d_in[17];
    const float* w_dt1  = (const float*)d_in[18];
    const float* b_dt1  = (const float*)d_in[19];
    const float* A_log1 = (const float*)d_in[20];
    const float* D1     = (const float*)d_in[21];
    const float* w_dbc2 = (const float*)d_in[22];
    const float* w_dt2  = (const float*)d_in[23];
    const float* b_dt2  = (const float*)d_in[24];
    const float* A_log2 = (const float*)d_in[25];
    const float* D2     = (const float*)d_in[26];

    float* ws = (float*)d_ws;
    size_t off = 0;
    float* LNF   = ws + off; off += (size_t)MTOT * ND;
    float* DBCF  = ws + off; off += (size_t)MTOT * 56;
    float* DELF  = ws + off; off += (size_t)MTOT * ND;
    float* YF    = ws + off; off += (size_t)MTOT * ND;
    float* LNB   = ws + off; off += (size_t)MTOT * ND;
    float* DBCB  = ws + off; off += (size_t)MTOT * 56;
    float* DELB  = ws + off; off += (size_t)MTOT * ND;
    float* YB    = ws + off; off += (size_t)MTOT * ND;

    // forward direction (recomputes LN1 + conv3 xp internally)
    dir_all<<<4096, 384, 0, stream>>>(x, 0, w_p2, b_p2, g_n, bt_n,
                                      w_cf, b_cf, g_nf, bt_nf,
                                      w_dbc1, w_dt1, b_dt1, LNF, DBCF, DELF);
    scan_naive<<<6, 256, 0, stream>>>(DELF, LNF, DBCF, A_log1, D1, YF);

    // backward direction (flipped sequence; output stays in flipped domain)
    dir_all<<<4096, 384, 0, stream>>>(x, 1, w_p2, b_p2, g_n, bt_n,
                                      w_cb, b_cb, g_nb, bt_nb,
                                      w_dbc2, w_dt2, b_dt2, LNB, DBCB, DELB);
    scan_naive<<<6, 256, 0, stream>>>(DELB, LNB, DBCB, A_log2, D2, YB);

    // final: recomputes LN1 + z1 gate internally; combine + projection + skip
    final_all<<<4096, 384, 0, stream>>>(x, w_p1, b_p1, g_n, bt_n,
                                        YF, YB, w_p3, b_p3, out);
}